// Round 13
// baseline (220.956 us; speedup 1.0000x reference)
//
#include <hip/hip_runtime.h>
#include <stdint.h>

// PinConv pipeline, round 23 (base = round 22, 215.4us best):
//  - gather_agg: TWO adjacent dst rows per wave. Kernel is latency-bound
//    (L3-resident y1b, dependent epack->y1b chains); two rows = two
//    independent chains per lane = 2x MLP at constant VALU. Wave count
//    50000 -> 25000 (still >> resident ~5k). Per-row accumulation order
//    unchanged -> bit-identical.
//  - everything else identical to round 22 (int2-packed edge records,
//    gload_lds+XOR-swizzle GEMMs, 128^2 gemm2 tile, no k_coffs, no fences).

#define BN_EPS 1e-5f
#define NSLOT 32

typedef __attribute__((ext_vector_type(8))) short bf16x8;
typedef __attribute__((ext_vector_type(4))) float f32x4;

#define GLDS16(g, l) __builtin_amdgcn_global_load_lds( \
    (__attribute__((address_space(1))) void*)(g), \
    (__attribute__((address_space(3))) void*)(l), 16, 0, 0)

static __device__ __forceinline__ unsigned short f2bf(float f) {
    uint32_t u = __builtin_bit_cast(uint32_t, f);
    u += 0x7fffu + ((u >> 16) & 1u);          // round-to-nearest-even
    return (unsigned short)(u >> 16);
}
static __device__ __forceinline__ float bf_lo(uint32_t u) {
    return __builtin_bit_cast(float, u << 16);
}
static __device__ __forceinline__ float bf_hi(uint32_t u) {
    return __builtin_bit_cast(float, u & 0xffff0000u);
}

static __device__ __forceinline__ void cast_blk(
    const float* __restrict__ src, unsigned short* __restrict__ dst,
    int n, int blk)
{
    int i = (blk * 256 + threadIdx.x) * 4;
    if (i + 3 < n) {
        float4 v = *(const float4*)(src + i);
        ushort4 o;
        o.x = f2bf(v.x); o.y = f2bf(v.y); o.z = f2bf(v.z); o.w = f2bf(v.w);
        *(ushort4*)(dst + i) = o;
    } else {
        for (int j = i; j < n; ++j) dst[j] = f2bf(src[j]);
    }
}

// Redundant per-block exclusive scan of ccnt[128].
static __device__ __forceinline__ void scan_ccnt(
    const int* __restrict__ ccnt, int* excl_out, int* v_out, int* w0s)
{
    const int t = threadIdx.x;
    int v = 0, incl = 0;
    if (t < 128) {
        v = ccnt[t];
        incl = v;
        const int lane = t & 63;
#pragma unroll
        for (int o = 1; o < 64; o <<= 1) {
            int u = __shfl_up(incl, o, 64);
            if (lane >= o) incl += u;
        }
        if (t == 63) *w0s = incl;
    }
    __syncthreads();
    int excl = 0;
    if (t < 128) excl = incl - v + ((t >> 6) ? *w0s : 0);
    *excl_out = excl;
    *v_out = v;
}

// ---------------------------------------------------------------------------
// Fused: blocks [0,CB) cast feat; [CB,CB+HB) coarse-histogram dst;
// [CB+HB, CB+HB+QB+WB) cast Q_w/W_w; remaining ZB blocks zero stats.
__global__ __launch_bounds__(256) void k_pre(
    const float* __restrict__ feat, unsigned short* __restrict__ featb, int nf,
    const int* __restrict__ dst, int* __restrict__ ccnt, int E, int CB, int HB,
    const float* __restrict__ Qw, unsigned short* __restrict__ Qwb,
    const float* __restrict__ Ww, unsigned short* __restrict__ Wwb,
    int* __restrict__ offs, int N, double* __restrict__ stats)
{
    int b = (int)blockIdx.x;
    if (b < CB) {
        if (b == 0 && threadIdx.x == 0) offs[N] = E;
        cast_blk(feat, featb, nf, b);
        return;
    }
    b -= CB;
    if (b >= HB) {
        b -= HB;
        if (b < 16) { cast_blk(Qw, Qwb, 128 * 128, b); return; }
        b -= 16;
        if (b < 32) { cast_blk(Ww, Wwb, 128 * 256, b); return; }
        b -= 32;
        // zero stats: 32 blocks x 256 threads x 16B = 128 KB
        uint4* p = (uint4*)stats;
        p[b * 256 + threadIdx.x] = make_uint4(0u, 0u, 0u, 0u);
        return;
    }
    __shared__ int hcnt[128];
    const int tid = threadIdx.x;
    if (tid < 128) hcnt[tid] = 0;
    __syncthreads();
    const int base_e = b * 2048;
#pragma unroll
    for (int j = 0; j < 8; ++j) {
        int e = base_e + j * 256 + tid;
        if (e < E) atomicAdd(&hcnt[dst[e] >> 9], 1);
    }
    __syncthreads();
    if (tid < 128 && hcnt[tid] > 0) atomicAdd(&ccnt[tid], hcnt[tid]);
}

// ---------------------------------------------------------------------------
// GEMM1 body (64x128 tile, gload_lds staging + XOR chunk swizzle):
// Y = relu(A @ B^T + bias) -> bf16. A = featb (K=128), B = Qwb [128][128].
static __device__ __forceinline__ void gemm1_body(
    int bid,
    const unsigned short* __restrict__ A,
    const unsigned short* __restrict__ Bb,
    const float* __restrict__ bias,
    unsigned short* __restrict__ Y,
    double* __restrict__ sum, double* __restrict__ sumsq, int N)
{
    __shared__ unsigned short As[64 * 64];    // linear [64][64], swizzled
    __shared__ unsigned short Bs[128 * 64];
    __shared__ float bsum_s[128], bsq_s[128];

    const int tid  = threadIdx.x;
    const int lane = tid & 63;
    const int wv   = tid >> 6;
    const int wr   = wv >> 1;
    const int wc   = wv & 1;
    const int m15  = lane & 15;
    const int quad = lane >> 4;
    const int r0   = bid * 64;

    if (tid < 128) { bsum_s[tid] = 0.f; bsq_s[tid] = 0.f; }

    const int lrow8 = lane >> 3;               // row within 8-row group
    const int ch    = (lane & 7) ^ lrow8;      // swizzled source chunk

    f32x4 acc[2][4];
#pragma unroll
    for (int rt = 0; rt < 2; ++rt)
#pragma unroll
        for (int ct = 0; ct < 4; ++ct)
            acc[rt][ct] = (f32x4){0.f, 0.f, 0.f, 0.f};

    for (int kc = 0; kc < 128; kc += 64) {
        // A tile: 8 groups of 8 rows (1KB each); wave wv -> groups wv*2..+1
#pragma unroll
        for (int jj = 0; jj < 2; ++jj) {
            int j = wv * 2 + jj;
            int row = j * 8 + lrow8;
            int gr  = r0 + row; if (gr >= N) gr = N - 1;
            GLDS16(A + (size_t)gr * 128 + kc + ch * 8, As + j * 512);
        }
        // B tile: 16 groups; wave wv -> groups wv*4..+3
#pragma unroll
        for (int jj = 0; jj < 4; ++jj) {
            int j = wv * 4 + jj;
            int row = j * 8 + lrow8;
            GLDS16(Bb + (size_t)row * 128 + kc + ch * 8, Bs + j * 512);
        }
        __syncthreads();

#pragma unroll
        for (int ks = 0; ks < 64; ks += 32) {
            const int chunk = quad + (ks >> 3);      // ks=32 -> +4
            bf16x8 af[2], bfr[4];
#pragma unroll
            for (int rt = 0; rt < 2; ++rt) {
                int arow = wr * 32 + rt * 16 + m15;
                af[rt] = *(const bf16x8*)(As + arow * 64 + ((chunk ^ (arow & 7)) * 8));
            }
#pragma unroll
            for (int ct = 0; ct < 4; ++ct) {
                int brow = wc * 64 + ct * 16 + m15;
                bfr[ct] = *(const bf16x8*)(Bs + brow * 64 + ((chunk ^ (brow & 7)) * 8));
            }
#pragma unroll
            for (int rt = 0; rt < 2; ++rt)
#pragma unroll
                for (int ct = 0; ct < 4; ++ct)
                    acc[rt][ct] = __builtin_amdgcn_mfma_f32_16x16x32_bf16(
                        af[rt], bfr[ct], acc[rt][ct], 0, 0, 0);
        }
        __syncthreads();
    }

#pragma unroll
    for (int ct = 0; ct < 4; ++ct) {
        int col = wc * 64 + ct * 16 + m15;
        float bz = bias[col];
        float s = 0.f, q = 0.f;
#pragma unroll
        for (int rt = 0; rt < 2; ++rt) {
#pragma unroll
            for (int reg = 0; reg < 4; ++reg) {
                int row = r0 + wr * 32 + rt * 16 + quad * 4 + reg;
                float vv = fmaxf(acc[rt][ct][reg] + bz, 0.f);
                if (row < N) {
                    Y[(size_t)row * 128 + col] = f2bf(vv);
                } else {
                    vv = 0.f;
                }
                s += vv; q = fmaf(vv, vv, q);
            }
        }
        s += __shfl_xor(s, 16, 64); s += __shfl_xor(s, 32, 64);
        q += __shfl_xor(q, 16, 64); q += __shfl_xor(q, 32, 64);
        if (quad == 0) {
            atomicAdd(&bsum_s[col], s);
            atomicAdd(&bsq_s[col], q);
        }
    }
    __syncthreads();
    if (tid < 128) {
        const int slot = (bid & (NSLOT - 1)) * 128;
        atomicAdd(&sum[slot + tid],   (double)bsum_s[tid]);
        atomicAdd(&sumsq[slot + tid], (double)bsq_s[tid]);
    }
}

// ---------------------------------------------------------------------------
// bn coef body: reduce 32 slots -> bn affine coefs. t in [0,128).
static __device__ __forceinline__ void bn_coef_body(
    int t, const double* __restrict__ sum, const double* __restrict__ sumsq,
    const float* __restrict__ gamma, const float* __restrict__ beta,
    float* __restrict__ a, float* __restrict__ b, double invN)
{
    double ms = 0.0, qs = 0.0;
#pragma unroll
    for (int s = 0; s < NSLOT; ++s) {
        ms += sum[s * 128 + t];
        qs += sumsq[s * 128 + t];
    }
    float mean = (float)(ms * invN);
    float var  = (float)(qs * invN) - mean * mean;
    float sc = rsqrtf(var + BN_EPS) * gamma[t];
    a[t] = sc;
    b[t] = fmaf(-mean, sc, beta[t]);
}

__global__ __launch_bounds__(128) void bn_coef(
    const double* __restrict__ sum, const double* __restrict__ sumsq,
    const float* __restrict__ gamma, const float* __restrict__ beta,
    float* __restrict__ a, float* __restrict__ b, double invN)
{
    bn_coef_body(threadIdx.x, sum, sumsq, gamma, beta, a, b, invN);
}

// ---------------------------------------------------------------------------
// bin body: bin edges into coarse buckets of 512 dsts. Record packed int2:
// x = src | (dst&511)<<17  (src<131072), y = w bits.
static __device__ __forceinline__ void bin_body(
    int bid,
    const int* __restrict__ src, const int* __restrict__ dst,
    const float* __restrict__ w,
    const int* __restrict__ ccnt, int* __restrict__ gofs,
    int2* __restrict__ tmp, int E)
{
    __shared__ int hcnt[128];
    __shared__ int hbase[128];
    __shared__ int w0s;
    const int tid = threadIdx.x;
    if (tid < 128) hcnt[tid] = 0;
    __syncthreads();

    int d8[8], s8[8], slot8[8];
    float w8[8];
#pragma unroll
    for (int j = 0; j < 8; ++j) {
        int e = bid * 2048 + j * 256 + tid;
        if (e < E) {
            d8[j] = dst[e]; s8[j] = src[e]; w8[j] = w[e];
            slot8[j] = atomicAdd(&hcnt[d8[j] >> 9], 1);
        } else d8[j] = -1;
    }
    __syncthreads();
    int excl, vcnt;
    scan_ccnt(ccnt, &excl, &vcnt, &w0s);
    if (tid < 128 && hcnt[tid] > 0)
        hbase[tid] = excl + atomicAdd(&gofs[tid], hcnt[tid]);
    __syncthreads();
#pragma unroll
    for (int j = 0; j < 8; ++j) {
        if (d8[j] >= 0) {
            int pos = hbase[d8[j] >> 9] + slot8[j];
            tmp[pos] = make_int2(s8[j] | ((d8[j] & 511) << 17),
                                 __float_as_int(w8[j]));
        }
    }
}

// fatB: blocks [0,HB) bin edges; blocks [HB,HB+GB) run gemm1 -> y1b bf16.
__global__ __launch_bounds__(256) void k_bin_gemm(
    const int* __restrict__ src, const int* __restrict__ dst,
    const float* __restrict__ w,
    const int* __restrict__ ccnt, int* __restrict__ gofs,
    int2* __restrict__ tmp, int E, int HB,
    const unsigned short* __restrict__ featb,
    const unsigned short* __restrict__ Qwb, const float* __restrict__ Qb,
    unsigned short* __restrict__ y1b,
    double* __restrict__ sum, double* __restrict__ sumsq, int N)
{
    if ((int)blockIdx.x < HB)
        bin_body(blockIdx.x, src, dst, w, ccnt, gofs, tmp, E);
    else
        gemm1_body(blockIdx.x - HB, featb, Qwb, Qb, y1b, sum, sumsq, N);
}

// ---------------------------------------------------------------------------
// refine body: per bucket — bases from redundant ccnt scan; count per-dst in
// LDS, scan (+bucket base), write offs slice, scatter to epack in dst order.
// tmp records packed: dstoff = x>>17, src = x & 0x1FFFF.
static __device__ __forceinline__ void refine_body(
    int b,
    const int2* __restrict__ tmp, const int* __restrict__ ccnt,
    int* __restrict__ offs, int2* __restrict__ epack, int N)
{
    __shared__ int hist[512];
    __shared__ int wpre[4];
    __shared__ int w0s;
    __shared__ int sbounds[2];
    const int d0   = b << 9;
    const int dlim = min(512, N - d0);
    const int tid  = threadIdx.x;
    const int lane = tid & 63, wv = tid >> 6;

    hist[tid] = 0; hist[tid + 256] = 0;
    __syncthreads();
    int excl, vcnt;
    scan_ccnt(ccnt, &excl, &vcnt, &w0s);
    if (tid == b) { sbounds[0] = excl; sbounds[1] = excl + vcnt; }
    __syncthreads();
    const int start = sbounds[0];
    const int end   = sbounds[1];

    for (int p = start + tid; p < end; p += 256)
        atomicAdd(&hist[tmp[p].x >> 17], 1);
    __syncthreads();

    int v0 = hist[2 * tid], v1 = hist[2 * tid + 1];
    int s = v0 + v1;
    int incl = s;
#pragma unroll
    for (int o = 1; o < 64; o <<= 1) {
        int t = __shfl_up(incl, o, 64);
        if (lane >= o) incl += t;
    }
    if (lane == 63) wpre[wv] = incl;
    __syncthreads();
    if (tid == 0) {
        int r = 0;
#pragma unroll
        for (int i = 0; i < 4; ++i) { int t = wpre[i]; wpre[i] = r; r += t; }
    }
    __syncthreads();
    int e0 = start + wpre[wv] + incl - s;
    if (2 * tid < dlim)     offs[d0 + 2 * tid]     = e0;
    if (2 * tid + 1 < dlim) offs[d0 + 2 * tid + 1] = e0 + v0;
    hist[2 * tid]     = e0;
    hist[2 * tid + 1] = e0 + v0;
    __syncthreads();

    for (int p = start + tid; p < end; p += 256) {
        int2 rec = tmp[p];
        int pos = atomicAdd(&hist[rec.x >> 17], 1);
        epack[pos] = make_int2(rec.x & 0x1FFFF, rec.y);
    }
}

// fat: block 0 = bn_coef1 reduce; blocks [1,NB] = refine buckets.
__global__ __launch_bounds__(256) void k_bnref(
    const double* __restrict__ sum, const double* __restrict__ sumsq,
    const float* __restrict__ gamma, const float* __restrict__ beta,
    float* __restrict__ a, float* __restrict__ b, double invN,
    const int2* __restrict__ tmp, const int* __restrict__ ccnt,
    int* __restrict__ offs, int2* __restrict__ epack, int N)
{
    if (blockIdx.x == 0) {
        if (threadIdx.x < 128)
            bn_coef_body(threadIdx.x, sum, sumsq, gamma, beta, a, b, invN);
        return;
    }
    refine_body((int)blockIdx.x - 1, tmp, ccnt, offs, epack, N);
}

// ---------------------------------------------------------------------------
// gather helpers: 8-col fma accumulate and reduce+write for one row.
static __device__ __forceinline__ void acc8(float (&A)[8], uint4 u, float w) {
    A[0] = fmaf(w, bf_lo(u.x), A[0]); A[1] = fmaf(w, bf_hi(u.x), A[1]);
    A[2] = fmaf(w, bf_lo(u.y), A[2]); A[3] = fmaf(w, bf_hi(u.y), A[3]);
    A[4] = fmaf(w, bf_lo(u.z), A[4]); A[5] = fmaf(w, bf_hi(u.z), A[5]);
    A[6] = fmaf(w, bf_lo(u.w), A[6]); A[7] = fmaf(w, bf_hi(u.w), A[7]);
}

static __device__ __forceinline__ void reduce_write8(
    float (&A)[8], float den, int r, int c, int hf,
    const unsigned short* __restrict__ y1b,
    const float* __restrict__ a, const float* __restrict__ b,
    unsigned short* __restrict__ aggb)
{
#pragma unroll
    for (int i = 0; i < 8; ++i) {
        A[i] += __shfl_xor(A[i], 16, 64);
        A[i] += __shfl_xor(A[i], 32, 64);
    }
    den += __shfl_xor(den, 16, 64); den += __shfl_xor(den, 32, 64);
    if (hf) return;
    float4 av0 = *(const float4*)(a + c);
    float4 av1 = *(const float4*)(a + c + 4);
    float4 bv0 = *(const float4*)(b + c);
    float4 bv1 = *(const float4*)(b + c + 4);
    float m[8];
    if (den != 0.f) {
        float inv = 1.f / den;
#pragma unroll
        for (int i = 0; i < 8; ++i) m[i] = A[i] * inv;
    } else {
        uint4 u = *(const uint4*)(y1b + (size_t)r * 128 + c);
        m[0] = bf_lo(u.x); m[1] = bf_hi(u.x); m[2] = bf_lo(u.y); m[3] = bf_hi(u.y);
        m[4] = bf_lo(u.z); m[5] = bf_hi(u.z); m[6] = bf_lo(u.w); m[7] = bf_hi(u.w);
    }
    uint4 o;
    o.x = (uint32_t)f2bf(fmaf(av0.x, m[0], bv0.x))
        | ((uint32_t)f2bf(fmaf(av0.y, m[1], bv0.y)) << 16);
    o.y = (uint32_t)f2bf(fmaf(av0.z, m[2], bv0.z))
        | ((uint32_t)f2bf(fmaf(av0.w, m[3], bv0.w)) << 16);
    o.z = (uint32_t)f2bf(fmaf(av1.x, m[4], bv1.x))
        | ((uint32_t)f2bf(fmaf(av1.y, m[5], bv1.y)) << 16);
    o.w = (uint32_t)f2bf(fmaf(av1.z, m[6], bv1.z))
        | ((uint32_t)f2bf(fmaf(av1.w, m[7], bv1.w)) << 16);
    *(uint4*)(aggb + (size_t)r * 128 + c) = o;
}

// ---------------------------------------------------------------------------
// TWO adjacent dst rows per wave; 16 lanes/edge, uint4 loads, 8 edges in
// flight per row chunk, both rows' chains interleaved in the joint loop.
// Reads raw relu y1b; applies bn affine to the weighted mean (or own row
// when den==0). Writes agg bf16. Per-row accumulation order identical to
// the 1-row version (bit-exact).
__global__ __launch_bounds__(256) void gather_agg(
    const unsigned short* __restrict__ y1b,
    const int* __restrict__ offs, const int2* __restrict__ epack,
    const float* __restrict__ a, const float* __restrict__ b,
    unsigned short* __restrict__ aggb, int N)
{
    const int wid  = (int)((blockIdx.x * 256u + threadIdx.x) >> 6);
    const int rA   = wid * 2;
    const int rB   = rA + 1;
    const int lane = threadIdx.x & 63;
    const int li   = lane & 15;     // owns columns 8*li .. 8*li+7
    const int hf   = lane >> 4;     // edge slot in quad (0..3)
    if (rA >= N) return;
    const int c = 8 * li;

    int pA = offs[rA];
    const int endA = offs[rA + 1];
    int pB = endA;                  // offs[rB] == offs[rA+1] (CSR)
    int endB = endA;
    if (rB < N) endB = offs[rB + 1];

    float aA[8] = {0.f, 0.f, 0.f, 0.f, 0.f, 0.f, 0.f, 0.f};
    float aB[8] = {0.f, 0.f, 0.f, 0.f, 0.f, 0.f, 0.f, 0.f};
    float denA = 0.f, denB = 0.f;

    // joint loop: both rows' 8-edge chunks interleaved (2x independent chains)
    while (pA + 7 < endA && pB + 7 < endB) {
        int2 eA0 = epack[pA + hf];
        int2 eA1 = epack[pA + 4 + hf];
        int2 eB0 = epack[pB + hf];
        int2 eB1 = epack[pB + 4 + hf];
        uint4 uA0 = *(const uint4*)(y1b + (size_t)eA0.x * 128 + c);
        uint4 uA1 = *(const uint4*)(y1b + (size_t)eA1.x * 128 + c);
        uint4 uB0 = *(const uint4*)(y1b + (size_t)eB0.x * 128 + c);
        uint4 uB1 = *(const uint4*)(y1b + (size_t)eB1.x * 128 + c);
        float wA0 = __int_as_float(eA0.y), wA1 = __int_as_float(eA1.y);
        float wB0 = __int_as_float(eB0.y), wB1 = __int_as_float(eB1.y);
        acc8(aA, uA0, wA0); acc8(aA, uA1, wA1);
        acc8(aB, uB0, wB0); acc8(aB, uB1, wB1);
        denA += wA0 + wA1;
        denB += wB0 + wB1;
        pA += 8; pB += 8;
    }
    // drain row A
    for (; pA + 7 < endA; pA += 8) {
        int2 e0 = epack[pA + hf];
        int2 e1 = epack[pA + 4 + hf];
        uint4 u0 = *(const uint4*)(y1b + (size_t)e0.x * 128 + c);
        uint4 u1 = *(const uint4*)(y1b + (size_t)e1.x * 128 + c);
        float w0 = __int_as_float(e0.y), w1 = __int_as_float(e1.y);
        acc8(aA, u0, w0); acc8(aA, u1, w1);
        denA += w0 + w1;
    }
    for (; pA < endA; pA += 4) {
        if (pA + hf < endA) {
            int2 e0 = epack[pA + hf];
            uint4 u0 = *(const uint4*)(y1b + (size_t)e0.x * 128 + c);
            float w0 = __int_as_float(e0.y);
            acc8(aA, u0, w0);
            denA += w0;
        }
    }
    // drain row B
    for (; pB + 7 < endB; pB += 8) {
        int2 e0 = epack[pB + hf];
        int2 e1 = epack[pB + 4 + hf];
        uint4 u0 = *(const uint4*)(y1b + (size_t)e0.x * 128 + c);
        uint4 u1 = *(const uint4*)(y1b + (size_t)e1.x * 128 + c);
        float w0 = __int_as_float(e0.y), w1 = __int_as_float(e1.y);
        acc8(aB, u0, w0); acc8(aB, u1, w1);
        denB += w0 + w1;
    }
    for (; pB < endB; pB += 4) {
        if (pB + hf < endB) {
            int2 e0 = epack[pB + hf];
            uint4 u0 = *(const uint4*)(y1b + (size_t)e0.x * 128 + c);
            float w0 = __int_as_float(e0.y);
            acc8(aB, u0, w0);
            denB += w0;
        }
    }

    reduce_write8(aA, denA, rA, c, hf, y1b, a, b, aggb);
    if (rB < N)
        reduce_write8(aB, denB, rB, c, hf, y1b, a, b, aggb);
}

// ---------------------------------------------------------------------------
// gemm2 standalone (K=256, A = [featb|aggb], 128x128 tile) -> y2 f32 + stats2.
// Staging via global_load_lds (width 16), linear LDS + XOR chunk swizzle.
__global__ __launch_bounds__(256) void gemm_bn2(
    const unsigned short* __restrict__ A_lo,
    const unsigned short* __restrict__ A_hi,
    const unsigned short* __restrict__ Bb,
    const float* __restrict__ bias,
    float* __restrict__ Y,
    double* __restrict__ sum, double* __restrict__ sumsq, int N)
{
    constexpr int K = 256;
    __shared__ unsigned short As[128 * 64];   // linear [128][64], swizzled
    __shared__ unsigned short Bs[128 * 64];
    __shared__ float bsum_s[128], bsq_s[128];

    const int tid  = threadIdx.x;
    const int lane = tid & 63;
    const int wv   = tid >> 6;
    const int wr   = wv >> 1;
    const int wc   = wv & 1;
    const int m15  = lane & 15;
    const int quad = lane >> 4;
    const int r0   = (int)blockIdx.x * 128;

    if (tid < 128) { bsum_s[tid] = 0.f; bsq_s[tid] = 0.f; }

    const int lrow8 = lane >> 3;               // row within 8-row group
    const int ch    = (lane & 7) ^ lrow8;      // swizzled source chunk

    f32x4 acc[4][4];
#pragma unroll
    for (int rt = 0; rt < 4; ++rt)
#pragma unroll
        for (int ct = 0; ct < 4; ++ct)
            acc[rt][ct] = (f32x4){0.f, 0.f, 0.f, 0.f};

    for (int kc = 0; kc < K; kc += 64) {
        const unsigned short* Ap = (kc < 128) ? A_lo : A_hi;
        const int koff = kc & 127;
        // A tile: 16 gload_lds of 1KB (8 rows each); wave wv -> groups wv*4..+3
#pragma unroll
        for (int jj = 0; jj < 4; ++jj) {
            int j = wv * 4 + jj;
            int row = j * 8 + lrow8;
            int gr  = r0 + row; if (gr >= N) gr = N - 1;
            GLDS16(Ap + (size_t)gr * 128 + koff + ch * 8, As + j * 512);
        }
        // B tile: same structure, source Bb[row][kc + ch*8]
#pragma unroll
        for (int jj = 0; jj < 4; ++jj) {
            int j = wv * 4 + jj;
            int row = j * 8 + lrow8;
            GLDS16(Bb + (size_t)row * K + kc + ch * 8, Bs + j * 512);
        }
        __syncthreads();

#pragma unroll
        for (int ks = 0; ks < 64; ks += 32) {
            const int chunk = quad + (ks >> 3);      // ks=32 -> +4
            bf16x8 af[4], bfr[4];
#pragma unroll
            for (int rt = 0; rt < 4; ++rt) {
                int arow = wr * 64 + rt * 16 + m15;
                af[rt] = *(const bf16x8*)(As + arow * 64 + ((chunk ^ (arow & 7)) * 8));
            }
#pragma unroll
            for (int ct = 0; ct < 4; ++ct) {
                int brow = wc * 64 + ct * 16 + m15;
                bfr[ct] = *(const bf16x8*)(Bs + brow * 64 + ((chunk ^ (brow & 7)) * 8));
            }
#pragma unroll
            for (int rt = 0; rt < 4; ++rt)
#pragma unroll
                for (int ct = 0; ct < 4; ++ct)
                    acc[rt][ct] = __builtin_amdgcn_mfma_f32_16x16x32_bf16(
                        af[rt], bfr[ct], acc[rt][ct], 0, 0, 0);
        }
        __syncthreads();
    }

#pragma unroll
    for (int ct = 0; ct < 4; ++ct) {
        int col = wc * 64 + ct * 16 + m15;
        float bz = bias[col];
        float s = 0.f, q = 0.f;
#pragma unroll
        for (int rt = 0; rt < 4; ++rt) {
#pragma unroll
            for (int reg = 0; reg < 4; ++reg) {
                int row = r0 + wr * 64 + rt * 16 + quad * 4 + reg;
                float vv = fmaxf(acc[rt][ct][reg] + bz, 0.f);
                if (row < N) {
                    Y[(size_t)row * 128 + col] = vv;
                } else {
                    vv = 0.f;
                }
                s += vv; q = fmaf(vv, vv, q);
            }
        }
        s += __shfl_xor(s, 16, 64); s += __shfl_xor(s, 32, 64);
        q += __shfl_xor(q, 16, 64); q += __shfl_xor(q, 32, 64);
        if (quad == 0) {
            atomicAdd(&bsum_s[col], s);
            atomicAdd(&bsq_s[col], q);
        }
    }
    __syncthreads();
    if (tid < 128) {
        const int slot = ((int)blockIdx.x & (NSLOT - 1)) * 128;
        atomicAdd(&sum[slot + tid],   (double)bsum_s[tid]);
        atomicAdd(&sumsq[slot + tid], (double)bsq_s[tid]);
    }
}

// ---------------------------------------------------------------------------
// bn2 affine (precomputed coefs) + row L2 normalize.
__global__ __launch_bounds__(256) void finalize(
    const float* __restrict__ Y2,
    const float* __restrict__ a, const float* __restrict__ b,
    float* __restrict__ out, int N)
{
    __shared__ float sa[128], sb[128];
    const int t = threadIdx.x;
    if (t < 128) { sa[t] = a[t]; sb[t] = b[t]; }
    __syncthreads();
    const int row  = (int)((blockIdx.x * 256u + t) >> 6);
    const int lane = t & 63;
    if (row >= N) return;
    const size_t base = (size_t)row * 128;
    float v0 = fmaf(sa[lane],      Y2[base + lane],      sb[lane]);
    float v1 = fmaf(sa[lane + 64], Y2[base + lane + 64], sb[lane + 64]);
    float ss = fmaf(v0, v0, v1 * v1);
#pragma unroll
    for (int o = 32; o; o >>= 1) ss += __shfl_xor(ss, o, 64);
    float nrm = sqrtf(ss);
    float inv = (nrm == 0.f) ? 1.f : 1.f / nrm;
    out[base + lane]      = v0 * inv;
    out[base + lane + 64] = v1 * inv;
}

// ---------------------------------------------------------------------------
extern "C" void kernel_launch(void* const* d_in, const int* in_sizes, int n_in,
                              void* d_out, int out_size, void* d_ws, size_t ws_size,
                              hipStream_t stream)
{
    const float* feat   = (const float*)d_in[0];
    const float* w      = (const float*)d_in[1];
    const float* Q_w    = (const float*)d_in[2];
    const float* Q_b    = (const float*)d_in[3];
    const float* W_w    = (const float*)d_in[4];
    const float* W_b    = (const float*)d_in[5];
    const float* gamma2 = (const float*)d_in[6];
    const float* beta2  = (const float*)d_in[7];
    const int*   src    = (const int*)d_in[8];
    const int*   dst    = (const int*)d_in[9];

    const int N = in_sizes[0] / 128;   // 50000
    const int E = in_sizes[1];         // 800000

    // workspace layout
    float*          y2    = (float*)d_ws;                            // N*128 f32
    unsigned short* featb = (unsigned short*)(y2 + (size_t)N * 128); // N*128 bf16
    unsigned short* aggb  = featb + (size_t)N * 128;                 // N*128 bf16
    unsigned short* y1b   = aggb + (size_t)N * 128;                  // N*128 bf16
    int2*  tmp    = (int2*)(y1b + (size_t)N * 128);                  // E (8B, packed)
    int2*  epack  = (int2*)(tmp + E);                                // E
    int*   offs   = (int*)(epack + E);                               // N+1
    float* coefs  = (float*)(offs + N + 1);                          // 512
    float* a1 = coefs, *b1 = coefs + 128, *a2 = coefs + 256, *b2 = coefs + 384;
    uintptr_t qp = ((uintptr_t)(coefs + 512) + 15) & ~(uintptr_t)15;
    unsigned short* Qwb = (unsigned short*)qp;                       // 128*128 bf16
    unsigned short* Wwb = Qwb + 128 * 128;                           // 128*256 bf16
    uintptr_t sp = ((uintptr_t)(Wwb + 128 * 256) + 15) & ~(uintptr_t)15;
    double* stats = (double*)sp;                                     // 4*NSLOT*128 <- zeroed in k_pre
    double* sum1   = stats;
    double* sumsq1 = stats + NSLOT * 128;
    double* sum2   = stats + 2 * NSLOT * 128;
    double* sumsq2 = stats + 3 * NSLOT * 128;
    int*   ccnt   = (int*)(stats + 4 * NSLOT * 128);                 // 128 <- zeroed
    int*   gofs   = ccnt + 128;                                      // 128 <- zeroed

    hipMemsetAsync(ccnt, 0, 256 * sizeof(int), stream);

    const double invN = 1.0 / (double)N;
    const int GB  = (N + 63) / 64;              // gemm1 blocks (782)
    const int GB2 = (N + 127) / 128;            // gemm2 blocks (391)
    const int NB = (N + 511) >> 9;              // coarse buckets (98)
    const int CB = (N * 128 / 4 + 255) / 256;   // feat cast blocks
    const int HB = (E + 2047) / 2048;           // histogram/bin blocks
    const int QB = 16;                          // Q_w cast blocks
    const int WB = 32;                          // W_w cast blocks
    const int ZB = 32;                          // stats-zero blocks (128KB)

    k_pre<<<CB + HB + QB + WB + ZB, 256, 0, stream>>>(
        feat, featb, N * 128, dst, ccnt, E, CB, HB,
        Q_w, Qwb, W_w, Wwb, offs, N, stats);

    // fatB: bin || gemm1 -> y1b bf16 + stats1 (bases via in-block ccnt scan)
    k_bin_gemm<<<HB + GB, 256, 0, stream>>>(
        src, dst, w, ccnt, gofs, tmp, E, HB,
        featb, Qwb, Q_b, y1b, sum1, sumsq1, N);

    // fat: bn_coef1 (block 0) || refine (blocks 1..NB)
    k_bnref<<<NB + 1, 256, 0, stream>>>(
        sum1, sumsq1, gamma2, beta2, a1, b1, invN,
        tmp, ccnt, offs, epack, N);

    // two rows per wave
    const int GW = (N + 1) / 2;                 // gather waves (25000)
    gather_agg<<<(GW * 64 + 255) / 256, 256, 0, stream>>>(
        y1b, offs, epack, a1, b1, aggb, N);

    gemm_bn2<<<GB2, 256, 0, stream>>>(
        featb, aggb, Wwb, W_b, y2, sum2, sumsq2, N);

    bn_coef<<<1, 128, 0, stream>>>(sum2, sumsq2, gamma2, beta2, a2, b2, invN);
    finalize<<<(N * 64 + 255) / 256, 256, 0, stream>>>(
        y2, a2, b2, (float*)d_out, N);
}